// Round 13
// baseline (283.274 us; speedup 1.0000x reference)
//
#include <hip/hip_runtime.h>

// ===== DIAGNOSTIC: R12 kernels + idempotent internal reps to surface
// per-kernel warm rates and counters above the 40us poison fills. =====

#define IN_F  1024
#define HID_F 1024
#define OUT_F 512
#define BATCH 128
#define REP_PRE 16
#define REP_KA  8
#define REP_KB  16

__device__ __forceinline__ float sigm(float v) { return 1.0f / (1.0f + __expf(-v)); }

typedef __attribute__((ext_vector_type(8))) float f32x8;
typedef __attribute__((ext_vector_type(4))) float f32x4;
typedef __attribute__((ext_vector_type(2))) float f32x2;

__device__ __forceinline__ f32x8 sld8(const float* p, int off_bytes) {
    f32x8 r;
    asm volatile("s_load_dwordx8 %0, %1, %2" : "=&s"(r) : "s"(p), "s"(off_bytes));
    return r;
}
__device__ __forceinline__ f32x4 sld4(const float* p, int off_bytes) {
    f32x4 r;
    asm volatile("s_load_dwordx4 %0, %1, %2" : "=&s"(r) : "s"(p), "s"(off_bytes));
    return r;
}
__device__ __forceinline__ void swait8x8(f32x8& a, f32x8& b, f32x8& c, f32x8& d,
                                         f32x8& e, f32x8& f, f32x8& g, f32x8& h) {
    asm volatile("s_waitcnt lgkmcnt(0)"
                 : "+s"(a), "+s"(b), "+s"(c), "+s"(d),
                   "+s"(e), "+s"(f), "+s"(g), "+s"(h));
}
__device__ __forceinline__ void swait4x8(f32x4& a, f32x4& b, f32x4& c, f32x4& d,
                                         f32x4& e, f32x4& f, f32x4& g, f32x4& h) {
    asm volatile("s_waitcnt lgkmcnt(0)"
                 : "+s"(a), "+s"(b), "+s"(c), "+s"(d),
                   "+s"(e), "+s"(f), "+s"(g), "+s"(h));
}

__device__ __forceinline__ f32x2 pair8(const f32x8& v, int k) {
    return f32x2{v[2 * k], v[2 * k + 1]};
}
__device__ __forceinline__ f32x2 pair4(const f32x4& v, int k) {
    return f32x2{v[2 * k], v[2 * k + 1]};
}

__global__ __launch_bounds__(256) void kPre(const float* __restrict__ x,
                                            const float* __restrict__ w1,
                                            const float* __restrict__ s1,
                                            const float* __restrict__ w2,
                                            float* __restrict__ xt,
                                            float* __restrict__ D2,
                                            float* __restrict__ PA64,
                                            float* __restrict__ W22) {
    const int bx = blockIdx.x, tid = threadIdx.x;
    if (bx < 64) {
        const int c = bx >> 2;
        const int j = (bx & 3) * 256 + tid;
        const float* w1l = w1; const float* s1l = s1;
        for (int rep = 0; rep < REP_PRE; ++rep) {
            asm volatile("" : "+s"(w1l), "+s"(s1l));
            float pa = 1.0f;
            float2* Dp = (float2*)D2;
#pragma unroll 4
            for (int ip = 0; ip < 32; ++ip) {
                const int i = c * 64 + ip * 2;
                const float wa = sigm(w1l[(size_t)i * HID_F + j]);
                const float sa = sigm(s1l[(size_t)i * HID_F + j]);
                const float wb = sigm(w1l[(size_t)(i + 1) * HID_F + j]);
                const float sb = sigm(s1l[(size_t)(i + 1) * HID_F + j]);
                const float A0 = 1.0f - wa * sa, C0 = wa * (2.0f * sa - 1.0f);
                const float A1 = 1.0f - wb * sb, C1 = wb * (2.0f * sb - 1.0f);
                Dp[(size_t)(i >> 1) * HID_F + j] = make_float2(C0 / A0, C1 / A1);
                pa *= A0 * A1;
            }
            PA64[(size_t)c * HID_F + j] = pa;
        }
    } else if (bx < 192) {
        const int idx = bx - 64;
        const int o = (idx & 1) * 256 + tid;
        const int jpg = idx >> 1;
        const float* w2l = w2;
        for (int rep = 0; rep < REP_PRE; ++rep) {
            asm volatile("" : "+s"(w2l));
            float2* Wp = (float2*)W22;
#pragma unroll
            for (int p = 0; p < 8; ++p) {
                const int jp = jpg * 8 + p;
                const float a = sigm(w2l[(size_t)(2 * jp) * OUT_F + o]);
                const float b = sigm(w2l[(size_t)(2 * jp + 1) * OUT_F + o]);
                Wp[(size_t)jp * OUT_F + o] = make_float2(a, b);
            }
        }
    } else {
        __shared__ float tile[32][33];
        const float* xl = x;
        for (int rep = 0; rep < REP_PRE; ++rep) {
            asm volatile("" : "+s"(xl));
            const int bt = bx - 192;
            const int i0 = (bt & 31) * 32, b0 = (bt >> 5) * 32;
            const int tx = tid & 31, ty = tid >> 5;
            __syncthreads();   // WAR guard for tile across reps
#pragma unroll
            for (int r = 0; r < 32; r += 8)
                tile[ty + r][tx] = xl[(size_t)(b0 + ty + r) * IN_F + i0 + tx];
            __syncthreads();
#pragma unroll
            for (int r = 0; r < 32; r += 8)
                xt[(size_t)(i0 + ty + r) * BATCH + b0 + tx] = tile[tx][ty + r];
        }
    }
}

__global__ __launch_bounds__(1024, 4) void kA(const float* __restrict__ D2,
                                              const float* __restrict__ PA64,
                                              const float* __restrict__ xt,
                                              float* __restrict__ ht) {
    __shared__ float ps[16][8][64];
    const int tid  = threadIdx.x;
    const int lane = tid & 63;
    const int wvu  = __builtin_amdgcn_readfirstlane(tid >> 6);
    const int jg = blockIdx.x, bg = blockIdx.y;
    const int j  = jg * 64 + lane;
    const int b0 = bg * 8;
    const int i0w = wvu * 64;

    const float* D2l = D2; const float* PAl = PA64; const float* xtl = xt;
    for (int rep = 0; rep < REP_KA; ++rep) {
        asm volatile("" : "+s"(D2l), "+s"(PAl), "+s"(xtl));
        const float2* dp = (const float2*)D2l + (size_t)(i0w >> 1) * HID_F + j;
        const float pa_v = PAl[(size_t)wvu * HID_F + j];

        const f32x2 one2 = {1.0f, 1.0f};
        f32x2 acc[4] = {one2, one2, one2, one2};

#define FMA2(XS, DSC) {                                          \
        const f32x2 ds_ = {DSC, DSC};                            \
        acc[0] *= __builtin_elementwise_fma(pair8(XS, 0), ds_, one2); \
        acc[1] *= __builtin_elementwise_fma(pair8(XS, 1), ds_, one2); \
        acc[2] *= __builtin_elementwise_fma(pair8(XS, 2), ds_, one2); \
        acc[3] *= __builtin_elementwise_fma(pair8(XS, 3), ds_, one2); }

#pragma unroll 1
        for (int bt = 0; bt < 8; ++bt) {
            const int ib = i0w + bt * 8;
            const float2 d0 = dp[(size_t)(bt * 4 + 0) * HID_F];
            const float2 d1 = dp[(size_t)(bt * 4 + 1) * HID_F];
            const float2 d2 = dp[(size_t)(bt * 4 + 2) * HID_F];
            const float2 d3 = dp[(size_t)(bt * 4 + 3) * HID_F];
            f32x8 x0 = sld8(xtl, ((ib + 0) * BATCH + b0) * 4);
            f32x8 x1 = sld8(xtl, ((ib + 1) * BATCH + b0) * 4);
            f32x8 x2 = sld8(xtl, ((ib + 2) * BATCH + b0) * 4);
            f32x8 x3 = sld8(xtl, ((ib + 3) * BATCH + b0) * 4);
            f32x8 x4 = sld8(xtl, ((ib + 4) * BATCH + b0) * 4);
            f32x8 x5 = sld8(xtl, ((ib + 5) * BATCH + b0) * 4);
            f32x8 x6 = sld8(xtl, ((ib + 6) * BATCH + b0) * 4);
            f32x8 x7 = sld8(xtl, ((ib + 7) * BATCH + b0) * 4);
            swait8x8(x0, x1, x2, x3, x4, x5, x6, x7);
            FMA2(x0, d0.x); FMA2(x1, d0.y);
            FMA2(x2, d1.x); FMA2(x3, d1.y);
            FMA2(x4, d2.x); FMA2(x5, d2.y);
            FMA2(x6, d3.x); FMA2(x7, d3.y);
        }
#undef FMA2
        const f32x2 pa2 = {pa_v, pa_v};
#pragma unroll
        for (int k = 0; k < 4; ++k) acc[k] *= pa2;

        __syncthreads();   // WAR guard: prior rep's combine readers done
#pragma unroll
        for (int k = 0; k < 4; ++k) {
            ps[wvu][2 * k][lane]     = acc[k].x;
            ps[wvu][2 * k + 1][lane] = acc[k].y;
        }
        __syncthreads();
        if (tid < 512) {
            const int bb = tid >> 6, jj = tid & 63;
            float p = 1.0f;
#pragma unroll
            for (int w = 0; w < 16; ++w) p *= ps[w][bb][jj];
            ht[(size_t)(jg * 64 + jj) * BATCH + b0 + bb] = p;
        }
    }
}

__global__ __launch_bounds__(1024, 4) void kB(const float* __restrict__ W22,
                                              const float* __restrict__ ht,
                                              float* __restrict__ out) {
    __shared__ float ps2[16][4][64];
    const int tid  = threadIdx.x;
    const int lane = tid & 63;
    const int wvu  = __builtin_amdgcn_readfirstlane(tid >> 6);
    const int og = blockIdx.x, bg = blockIdx.y;
    const int o  = og * 64 + lane;
    const int b0 = bg * 4;
    const int j0w = wvu * 64;

    const float* Wl = W22; const float* hl = ht;
    for (int rep = 0; rep < REP_KB; ++rep) {
        asm volatile("" : "+s"(Wl), "+s"(hl));
        const float2* wp = (const float2*)Wl + (size_t)(j0w >> 1) * OUT_F + o;

        const f32x2 one2 = {1.0f, 1.0f};
        f32x2 acc[2] = {one2, one2};

#define FMB2(HS, WSC) {                                          \
        const f32x2 ws_ = {WSC, WSC};                            \
        acc[0] *= __builtin_elementwise_fma(-pair4(HS, 0), ws_, one2); \
        acc[1] *= __builtin_elementwise_fma(-pair4(HS, 1), ws_, one2); }

#pragma unroll 1
        for (int bt = 0; bt < 8; ++bt) {
            const int jb = j0w + bt * 8;
            const float2 w0 = wp[(size_t)(bt * 4 + 0) * OUT_F];
            const float2 w1_ = wp[(size_t)(bt * 4 + 1) * OUT_F];
            const float2 w2_ = wp[(size_t)(bt * 4 + 2) * OUT_F];
            const float2 w3_ = wp[(size_t)(bt * 4 + 3) * OUT_F];
            f32x4 h0 = sld4(hl, ((jb + 0) * BATCH + b0) * 4);
            f32x4 h1 = sld4(hl, ((jb + 1) * BATCH + b0) * 4);
            f32x4 h2 = sld4(hl, ((jb + 2) * BATCH + b0) * 4);
            f32x4 h3 = sld4(hl, ((jb + 3) * BATCH + b0) * 4);
            f32x4 h4 = sld4(hl, ((jb + 4) * BATCH + b0) * 4);
            f32x4 h5 = sld4(hl, ((jb + 5) * BATCH + b0) * 4);
            f32x4 h6 = sld4(hl, ((jb + 6) * BATCH + b0) * 4);
            f32x4 h7 = sld4(hl, ((jb + 7) * BATCH + b0) * 4);
            swait4x8(h0, h1, h2, h3, h4, h5, h6, h7);
            FMB2(h0, w0.x); FMB2(h1, w0.y);
            FMB2(h2, w1_.x); FMB2(h3, w1_.y);
            FMB2(h4, w2_.x); FMB2(h5, w2_.y);
            FMB2(h6, w3_.x); FMB2(h7, w3_.y);
        }
#undef FMB2

        __syncthreads();   // WAR guard
#pragma unroll
        for (int k = 0; k < 2; ++k) {
            ps2[wvu][2 * k][lane]     = acc[k].x;
            ps2[wvu][2 * k + 1][lane] = acc[k].y;
        }
        __syncthreads();
        if (tid < 256) {
            const int bb = tid >> 6, oo = tid & 63;
            float p = 1.0f;
#pragma unroll
            for (int w = 0; w < 16; ++w) p *= ps2[w][bb][oo];
            out[(size_t)(b0 + bb) * OUT_F + og * 64 + oo] = 1.0f - p;
        }
    }
}

extern "C" void kernel_launch(void* const* d_in, const int* in_sizes, int n_in,
                              void* d_out, int out_size, void* d_ws, size_t ws_size,
                              hipStream_t stream) {
    const float* x  = (const float*)d_in[0];
    const float* w1 = (const float*)d_in[1];
    const float* s1 = (const float*)d_in[2];
    const float* w2 = (const float*)d_in[3];
    float* out = (float*)d_out;

    float* D2   = (float*)d_ws;
    float* PA64 = D2 + (size_t)IN_F * HID_F;
    float* W22  = PA64 + (size_t)16 * HID_F;
    float* xt   = W22 + (size_t)HID_F * OUT_F;
    float* ht   = xt + (size_t)IN_F * BATCH;

    kPre<<<320, 256, 0, stream>>>(x, w1, s1, w2, xt, D2, PA64, W22);
    kA<<<dim3(16, 16), 1024, 0, stream>>>(D2, PA64, xt, ht);
    kB<<<dim3(8, 32), 1024, 0, stream>>>(W22, ht, out);
}

// Round 14
// 30.676 us; speedup vs baseline: 9.2343x; 9.2343x over previous
//
#include <hip/hip_runtime.h>

#define IN_F  1024
#define HID_F 1024
#define OUT_F 512
#define BATCH 128

typedef __attribute__((ext_vector_type(8))) float f32x8;
typedef __attribute__((ext_vector_type(2))) float f32x2;

__device__ __forceinline__ float sigm(float v) {
    return __builtin_amdgcn_rcpf(1.0f + __expf(-v));
}

// Scalar-pipe broadcast loads (wave-uniform addr -> SGPRs). SMEM completes
// out-of-order: only lgkmcnt(0) is safe, so batches are drained whole; the
// callers double-buffer two batches so the drain overlaps compute.
__device__ __forceinline__ f32x8 sld8(const float* p, int off_bytes) {
    f32x8 r;
    asm volatile("s_load_dwordx8 %0, %1, %2" : "=&s"(r) : "s"(p), "s"(off_bytes));
    return r;
}
__device__ __forceinline__ void swaitA(f32x8& a, f32x8& b, f32x8& c, f32x8& d) {
    asm volatile("s_waitcnt lgkmcnt(0)" : "+s"(a), "+s"(b), "+s"(c), "+s"(d));
}
__device__ __forceinline__ void swaitB(f32x8& a, f32x8& b) {
    asm volatile("s_waitcnt lgkmcnt(0)" : "+s"(a), "+s"(b));
}

// kPre: [0,512):  S1 — 8-i subchunk sc=bx>>2, j=(bx&3)*256+tid:
//                 D[i][j] = C*rcp(A), PA8[sc][j] = prod A; A=1-ws, C=w(2s-1)
//       [512,1024): S2 — W22 = sigm(w2), layout [j][o] (same as w2)
__global__ __launch_bounds__(256) void kPre(const float* __restrict__ w1,
                                            const float* __restrict__ s1,
                                            const float* __restrict__ w2,
                                            float* __restrict__ D,
                                            float* __restrict__ PA8,
                                            float* __restrict__ W22) {
    const int bx = blockIdx.x, tid = threadIdx.x;
    if (bx < 512) {
        const int sc = bx >> 2;                 // 0..127
        const int j  = (bx & 3) * 256 + tid;
        float pa = 1.0f;
#pragma unroll
        for (int ii = 0; ii < 8; ++ii) {
            const int i = sc * 8 + ii;
            const float w = sigm(w1[(size_t)i * HID_F + j]);
            const float s = sigm(s1[(size_t)i * HID_F + j]);
            const float A = 1.0f - w * s;
            const float C = w * (2.0f * s - 1.0f);
            D[(size_t)i * HID_F + j] = C * __builtin_amdgcn_rcpf(A);
            pa *= A;
        }
        PA8[(size_t)sc * HID_F + j] = pa;
    } else {
        const int e = ((bx - 512) * 256 + tid) * 4;
        const float4 v = *(const float4*)(w2 + e);
        float4 r;
        r.x = sigm(v.x); r.y = sigm(v.y); r.z = sigm(v.z); r.w = sigm(v.w);
        *(float4*)(W22 + e) = r;
    }
}

// kA: layer 1 -> ht[b][j]. grid (8 jg, 32 bg) x 1024 thr (16 waves).
// Lane owns j-pair (j0+2l, j0+2l+1): D is a per-lane coalesced float2 VMEM
// stream (vmcnt-pipelined by compiler). x[b][i] read via s_load_dwordx8,
// double-buffered 2-deep (issue t+1, compute t, drain). Packed f32x2 math.
__global__ __launch_bounds__(1024, 4) void kA(const float* __restrict__ D,
                                              const float* __restrict__ PA8,
                                              const float* __restrict__ xf,
                                              float* __restrict__ ht) {
    __shared__ float ps[16][4][128];   // 32 KB
    const int tid  = threadIdx.x;
    const int lane = tid & 63;
    const int wvu  = __builtin_amdgcn_readfirstlane(tid >> 6);  // 0..15
    const int j0 = blockIdx.x * 128, b0 = blockIdx.y * 4;
    const int i0w = wvu * 64;

    const f32x2* dpp = (const f32x2*)D + (size_t)j0 / 2 + lane;
    const f32x2 one2 = {1.0f, 1.0f};
    f32x2 acc0 = one2, acc1 = one2, acc2 = one2, acc3 = one2;

#define LOADX(S, bt) { \
        S##0 = sld8(xf, ((b0 + 0) * IN_F + i0w + (bt) * 8) * 4); \
        S##1 = sld8(xf, ((b0 + 1) * IN_F + i0w + (bt) * 8) * 4); \
        S##2 = sld8(xf, ((b0 + 2) * IN_F + i0w + (bt) * 8) * 4); \
        S##3 = sld8(xf, ((b0 + 3) * IN_F + i0w + (bt) * 8) * 4); }
#define COMPX(S, bt) { \
        _Pragma("unroll") \
        for (int ii = 0; ii < 8; ++ii) { \
            const f32x2 d = dpp[(size_t)(i0w + (bt) * 8 + ii) * (HID_F / 2)]; \
            f32x2 t; \
            t = f32x2{S##0[ii], S##0[ii]}; acc0 *= __builtin_elementwise_fma(t, d, one2); \
            t = f32x2{S##1[ii], S##1[ii]}; acc1 *= __builtin_elementwise_fma(t, d, one2); \
            t = f32x2{S##2[ii], S##2[ii]}; acc2 *= __builtin_elementwise_fma(t, d, one2); \
            t = f32x2{S##3[ii], S##3[ii]}; acc3 *= __builtin_elementwise_fma(t, d, one2); } }

    f32x8 A0, A1, A2, A3, B0, B1, B2, B3;
    LOADX(A, 0); swaitA(A0, A1, A2, A3);
    LOADX(B, 1); COMPX(A, 0); swaitA(B0, B1, B2, B3);
    LOADX(A, 2); COMPX(B, 1); swaitA(A0, A1, A2, A3);
    LOADX(B, 3); COMPX(A, 2); swaitA(B0, B1, B2, B3);
    LOADX(A, 4); COMPX(B, 3); swaitA(A0, A1, A2, A3);
    LOADX(B, 5); COMPX(A, 4); swaitA(B0, B1, B2, B3);
    LOADX(A, 6); COMPX(B, 5); swaitA(A0, A1, A2, A3);
    LOADX(B, 7); COMPX(A, 6); swaitA(B0, B1, B2, B3);
    COMPX(B, 7);
#undef LOADX
#undef COMPX

    // apply prod(A) for this wave's 64 i (8 PA8 rows), per-lane float2 loads
    {
        const f32x2* pap = (const f32x2*)PA8 + (size_t)(8 * wvu) * (HID_F / 2)
                           + j0 / 2 + lane;
        f32x2 pa = pap[0];
#pragma unroll
        for (int u = 1; u < 8; ++u) pa *= pap[(size_t)u * (HID_F / 2)];
        acc0 *= pa; acc1 *= pa; acc2 *= pa; acc3 *= pa;
    }

    *(f32x2*)&ps[wvu][0][2 * lane] = acc0;
    *(f32x2*)&ps[wvu][1][2 * lane] = acc1;
    *(f32x2*)&ps[wvu][2][2 * lane] = acc2;
    *(f32x2*)&ps[wvu][3][2 * lane] = acc3;
    __syncthreads();
    if (tid < 512) {
        const int b = tid >> 7, j = tid & 127;
        float p = 1.0f;
#pragma unroll
        for (int w = 0; w < 16; ++w) p *= ps[w][b][j];
        ht[(size_t)(b0 + b) * HID_F + j0 + j] = p;   // coalesced 512B rows
    }
}

// kB: layer 2 -> out. grid (4 og, 64 bg) x 1024 thr (16 waves).
// Lane owns o-pair; W22 per-lane float2 stream; h[b][j] via s_load 2-deep.
__global__ __launch_bounds__(1024, 4) void kB(const float* __restrict__ W22,
                                              const float* __restrict__ ht,
                                              float* __restrict__ out) {
    __shared__ float ps2[16][2][128];  // 16 KB
    const int tid  = threadIdx.x;
    const int lane = tid & 63;
    const int wvu  = __builtin_amdgcn_readfirstlane(tid >> 6);
    const int o0 = blockIdx.x * 128, b0 = blockIdx.y * 2;
    const int j0w = wvu * 64;

    const f32x2* wpp = (const f32x2*)W22 + (size_t)o0 / 2 + lane;
    const f32x2 one2 = {1.0f, 1.0f};
    f32x2 acc0 = one2, acc1 = one2;

#define LOADH(S, bt) { \
        S##0 = sld8(ht, ((b0 + 0) * HID_F + j0w + (bt) * 8) * 4); \
        S##1 = sld8(ht, ((b0 + 1) * HID_F + j0w + (bt) * 8) * 4); }
#define COMPH(S, bt) { \
        _Pragma("unroll") \
        for (int jj = 0; jj < 8; ++jj) { \
            const f32x2 wv = wpp[(size_t)(j0w + (bt) * 8 + jj) * (OUT_F / 2)]; \
            f32x2 t; \
            t = f32x2{-S##0[jj], -S##0[jj]}; acc0 *= __builtin_elementwise_fma(t, wv, one2); \
            t = f32x2{-S##1[jj], -S##1[jj]}; acc1 *= __builtin_elementwise_fma(t, wv, one2); } }

    f32x8 A0, A1, B0, B1;
    LOADH(A, 0); swaitB(A0, A1);
    LOADH(B, 1); COMPH(A, 0); swaitB(B0, B1);
    LOADH(A, 2); COMPH(B, 1); swaitB(A0, A1);
    LOADH(B, 3); COMPH(A, 2); swaitB(B0, B1);
    LOADH(A, 4); COMPH(B, 3); swaitB(A0, A1);
    LOADH(B, 5); COMPH(A, 4); swaitB(B0, B1);
    LOADH(A, 6); COMPH(B, 5); swaitB(A0, A1);
    LOADH(B, 7); COMPH(A, 6); swaitB(B0, B1);
    COMPH(B, 7);
#undef LOADH
#undef COMPH

    *(f32x2*)&ps2[wvu][0][2 * lane] = acc0;
    *(f32x2*)&ps2[wvu][1][2 * lane] = acc1;
    __syncthreads();
    if (tid < 256) {
        const int b = tid >> 7, o = tid & 127;
        float p = 1.0f;
#pragma unroll
        for (int w = 0; w < 16; ++w) p *= ps2[w][b][o];
        out[(size_t)(b0 + b) * OUT_F + o0 + o] = 1.0f - p;   // coalesced
    }
}

extern "C" void kernel_launch(void* const* d_in, const int* in_sizes, int n_in,
                              void* d_out, int out_size, void* d_ws, size_t ws_size,
                              hipStream_t stream) {
    const float* x  = (const float*)d_in[0];
    const float* w1 = (const float*)d_in[1];
    const float* s1 = (const float*)d_in[2];
    const float* w2 = (const float*)d_in[3];
    float* out = (float*)d_out;

    // ws (floats): D 4MB | PA8 512KB | W22 2MB | ht 512KB
    float* D   = (float*)d_ws;
    float* PA8 = D + (size_t)IN_F * HID_F;
    float* W22 = PA8 + (size_t)128 * HID_F;
    float* ht  = W22 + (size_t)HID_F * OUT_F;

    kPre<<<1024, 256, 0, stream>>>(w1, s1, w2, D, PA8, W22);
    kA<<<dim3(8, 32), 1024, 0, stream>>>(D, PA8, x, ht);
    kB<<<dim3(4, 64), 1024, 0, stream>>>(W22, ht, out);
}